// Round 8
// baseline (298.382 us; speedup 1.0000x reference)
//
#include <hip/hip_runtime.h>
#include <math.h>

typedef unsigned int u32;

#define NBKT 65536   // 16-bit prefix buckets
#define RANK_CAP 32768

// ===== Bit-exact replica of XLA's f32 tanh (ElementalIrEmitter::EmitTanh) =====
// clamp x to [-9,9]; rational poly P(x)/Q(x) in strict f32 (no FMA); |x|<0.0004 -> x
__device__ __forceinline__ float xla_tanhf(float x) {
    float xc = fminf(fmaxf(x, -9.0f), 9.0f);
    float x2 = __fmul_rn(xc, xc);
    float p = -2.76076847742355e-16f;
    p = __fadd_rn(__fmul_rn(p, x2),  2.00018790482477e-13f);
    p = __fadd_rn(__fmul_rn(p, x2), -8.60467152213735e-11f);
    p = __fadd_rn(__fmul_rn(p, x2),  5.12229709037114e-08f);
    p = __fadd_rn(__fmul_rn(p, x2),  1.48572235717979e-05f);
    p = __fadd_rn(__fmul_rn(p, x2),  6.37261928875436e-04f);
    p = __fadd_rn(__fmul_rn(p, x2),  4.89352455891786e-03f);
    p = __fmul_rn(xc, p);
    float q = 1.19825839466702e-06f;
    q = __fadd_rn(__fmul_rn(q, x2),  1.18534705686654e-04f);
    q = __fadd_rn(__fmul_rn(q, x2),  2.26843463243900e-03f);
    q = __fadd_rn(__fmul_rn(q, x2),  4.89352518554385e-03f);
    float r = p / q;                     // IEEE f32 divide (default, no fast-math)
    return (fabsf(x) < 0.0004f) ? x : r;
}

// ascending u32 order of key_desc(f) == DESCENDING float order of f
__device__ __forceinline__ u32 key_desc(float f) {
    u32 u = __float_as_uint(f);
    u = (u & 0x80000000u) ? ~u : (u | 0x80000000u);
    return ~u;
}

__global__ void k_zero(u32* __restrict__ p, int n) {
    int i = blockIdx.x * blockDim.x + threadIdx.x;
    if (i < n) p[i] = 0;
}

// int64 little-endian with small nonnegative values => odd 32-bit words all zero.
__global__ void k_detect(const int* __restrict__ p, int nprobe, u32* __restrict__ flag) {
    int i = blockIdx.x * blockDim.x + threadIdx.x;
    if (i < nprobe) {
        if (p[2 * i + 1] != 0) atomicOr(flag, 1u);
    }
}

// XLA-exact tanh table (== reference's sort key bits), cluster init, histogram
__global__ void k_prep(const float* __restrict__ score, float* __restrict__ s,
                       int* __restrict__ cluster, u32* __restrict__ hist, int N) {
    int i = blockIdx.x * blockDim.x + threadIdx.x;
    if (i < N) {
        float t = xla_tanhf(score[i]);
        s[i] = t;
        cluster[i] = -1;
        atomicAdd(&hist[key_desc(t) >> 16], 1u);
    }
}

// exclusive scan of 65536 bucket counts; scan[NBKT]=N. One block of 256.
__global__ void k_scanB(const u32* __restrict__ hist, u32* __restrict__ scan) {
    __shared__ u32 part[256];
    int t = threadIdx.x;
    int base = t * 256;
    u32 sum = 0;
    for (int j = 0; j < 256; ++j) sum += hist[base + j];
    part[t] = sum;
    __syncthreads();
    if (t == 0) {
        u32 acc = 0;
        for (int j = 0; j < 256; ++j) { u32 tmp = part[j]; part[j] = acc; acc += tmp; }
    }
    __syncthreads();
    u32 run = part[t];
    for (int j = 0; j < 256; ++j) { scan[base + j] = run; run += hist[base + j]; }
    if (t == 255) scan[NBKT] = run;
}

// scatter (tanh-key, idx) into bucket range (intra-bucket order arbitrary; re-ranked after)
__global__ void k_scat(const float* __restrict__ s, const u32* __restrict__ scan,
                       u32* __restrict__ cursor, u32* __restrict__ skey,
                       u32* __restrict__ sidx, int N) {
    int i = blockIdx.x * blockDim.x + threadIdx.x;
    if (i < N) {
        u32 kk = key_desc(s[i]);
        u32 b = kk >> 16;
        u32 pos = scan[b] + atomicAdd(&cursor[b], 1u);
        if (pos < (u32)N) { skey[pos] = kk; sidx[pos] = (u32)i; }
    }
}

// exact deterministic rank within bucket: lexicographic (key asc, idx asc)
// == top_k on XLA-tanh, descending, lowest-index-first ties (lax.top_k semantics)
__global__ void k_rank(const u32* __restrict__ scan, const u32* __restrict__ skey,
                       const u32* __restrict__ sidx, u32* __restrict__ pay, int N) {
    int i = blockIdx.x * blockDim.x + threadIdx.x;
    if (i < N) {
        u32 kp = skey[i], ip = sidx[i];
        u32 b = kp >> 16;
        u32 lo = scan[b], hi = scan[b + 1];
        if (hi > (u32)N) hi = (u32)N;
        if (hi > lo + RANK_CAP) hi = lo + RANK_CAP;
        u32 r = lo;
        for (u32 q = lo; q < hi; ++q) {
            u32 kq = skey[q];
            if (kq < kp || (kq == kp && sidx[q] < ip)) ++r;
        }
        if (r < (u32)N) pay[r] = ip;
    }
}

__global__ void k_perm(const u32* __restrict__ pay, const float* __restrict__ s,
                       const int* __restrict__ ntype, const u32* __restrict__ ntFlag,
                       int* __restrict__ cluster,
                       float* __restrict__ o_nt, float* __restrict__ o_perm,
                       float* __restrict__ o_vals, int k, int N) {
    int r = blockIdx.x * blockDim.x + threadIdx.x;
    if (r < k) {
        u32 p = pay[r];
        if (p >= (u32)N) p = 0;          // defensive clamp
        cluster[p] = r;
        o_perm[r] = (float)p;
        o_vals[r] = s[p];
        int nt = (*ntFlag == 0u) ? ntype[2 * (size_t)p] : ntype[p];  // int64 vs int32
        o_nt[r] = (float)nt;
    }
}

__global__ void k_gx(const u32* __restrict__ pay, const float* __restrict__ s,
                     const float4* __restrict__ x4, float4* __restrict__ out4,
                     int k, int Dv, int N) {
    int idx = blockIdx.x * blockDim.x + threadIdx.x;
    if (idx < k * Dv) {
        int r = idx / Dv;
        int c = idx - r * Dv;
        u32 p = pay[r];
        if (p >= (u32)N) p = 0;          // defensive clamp
        float v = s[p];
        float4 a = x4[(size_t)p * Dv + c];
        a.x *= v; a.y *= v; a.z *= v; a.w *= v;
        out4[idx] = a;
    }
}

__global__ void k_edges(const int* __restrict__ ei, const u32* __restrict__ eiFlag,
                        const float* __restrict__ elen,
                        const int* __restrict__ cluster,
                        float* __restrict__ o_ei, float* __restrict__ o_len,
                        float* __restrict__ o_mask, int E, int N) {
    int e = blockIdx.x * blockDim.x + threadIdx.x;
    if (e < E) {
        bool w64 = (*eiFlag == 0u);      // int64 device layout
        int a = w64 ? ei[2 * (size_t)e] : ei[e];
        int b = w64 ? ei[2 * ((size_t)E + (size_t)e)] : ei[E + e];
        bool ok = ((u32)a < (u32)N) && ((u32)b < (u32)N);   // defensive
        int r = ok ? cluster[a] : -1;
        int c = ok ? cluster[b] : -1;
        bool m = (r >= 0) && (c >= 0);
        o_ei[e]     = m ? (float)r : 0.0f;
        o_ei[E + e] = m ? (float)c : 0.0f;
        o_len[e]    = m ? elen[e] : 0.0f;
        o_mask[e]   = m ? 1.0f : 0.0f;
    }
}

__global__ void k_eattr(const float4* __restrict__ attr4, const float* __restrict__ mask,
                        float4* __restrict__ out4, int E, int DEv) {
    int idx = blockIdx.x * blockDim.x + threadIdx.x;
    if (idx < E * DEv) {
        int e = idx / DEv;               // DEv = DE/4 = 4
        float4 a = attr4[idx];
        if (mask[e] == 0.0f) { a.x = 0.f; a.y = 0.f; a.z = 0.f; a.w = 0.f; }
        out4[idx] = a;
    }
}

extern "C" void kernel_launch(void* const* d_in, const int* in_sizes, int n_in,
                              void* d_out, int out_size, void* d_ws, size_t ws_size,
                              hipStream_t stream) {
    const float* x     = (const float*)d_in[0];
    const float* score = (const float*)d_in[1];
    const int*   ei    = (const int*)d_in[2];
    const float* eattr = (const float*)d_in[3];
    const int*   ntype = (const int*)d_in[4];
    const float* elen  = (const float*)d_in[5];

    const int N  = in_sizes[1];
    const int D  = in_sizes[0] / N;
    const int E  = in_sizes[5];
    const int DE = in_sizes[3] / E;
    const int k  = (N + 1) / 2;     // ceil(0.5 * N)

    // d_out is FLOAT32. RETURN-ORDER layout, f32 elements:
    // x_p | edge_index | edge_attr_p | node_type | perm | vals | edge_lengths | edge_mask
    float* out = (float*)d_out;
    const size_t o_xp    = 0;
    const size_t o_ei    = o_xp    + (size_t)k * D;
    const size_t o_eattr = o_ei    + 2 * (size_t)E;
    const size_t o_nt    = o_eattr + (size_t)E * DE;
    const size_t o_perm  = o_nt    + (size_t)k;
    const size_t o_vals  = o_perm  + (size_t)k;
    const size_t o_elen  = o_vals  + (size_t)k;
    const size_t o_emask = o_elen  + (size_t)E;

    char* ws = (char*)d_ws;
    float* s     = (float*)ws;   ws += 4 * (size_t)N;
    u32* hist    = (u32*)ws;     ws += 4 * (size_t)NBKT;
    u32* cursor  = (u32*)ws;     ws += 4 * (size_t)NBKT;   // contiguous with hist
    u32* flags   = (u32*)ws;     ws += 4 * 2;              // contiguous: zeroed together
    u32* scan    = (u32*)ws;     ws += 4 * ((size_t)NBKT + 2);
    u32* skey    = (u32*)ws;     ws += 4 * (size_t)N;
    u32* sidx    = (u32*)ws;     ws += 4 * (size_t)N;
    u32* pay     = (u32*)ws;     ws += 4 * (size_t)N;
    int* cluster = (int*)ws;     ws += 4 * (size_t)N;

    const int nbN = (N + 255) / 256;
    k_zero<<<(2 * NBKT + 2 + 255) / 256, 256, 0, stream>>>(hist, 2 * NBKT + 2);
    k_detect<<<8, 256, 0, stream>>>(ei, 2048, &flags[0]);
    k_detect<<<8, 256, 0, stream>>>(ntype, 2048, &flags[1]);
    k_prep<<<nbN, 256, 0, stream>>>(score, s, cluster, hist, N);
    k_scanB<<<1, 256, 0, stream>>>(hist, scan);
    k_scat<<<nbN, 256, 0, stream>>>(s, scan, cursor, skey, sidx, N);
    k_rank<<<nbN, 256, 0, stream>>>(scan, skey, sidx, pay, N);

    k_perm<<<(k + 255) / 256, 256, 0, stream>>>(pay, s, ntype, &flags[1], cluster,
                                                out + o_nt, out + o_perm, out + o_vals, k, N);
    const int Dv = D / 4;
    const int gx = k * Dv;
    k_gx<<<(gx + 255) / 256, 256, 0, stream>>>(pay, s, (const float4*)x,
                                               (float4*)(out + o_xp), k, Dv, N);
    k_edges<<<(E + 255) / 256, 256, 0, stream>>>(ei, &flags[0], elen, cluster,
                                                 out + o_ei, out + o_elen, out + o_emask, E, N);
    const int DEv = DE / 4;
    const int ga = E * DEv;
    k_eattr<<<(ga + 255) / 256, 256, 0, stream>>>((const float4*)eattr, out + o_emask,
                                                  (float4*)(out + o_eattr), E, DEv);
}